// Round 3
// baseline (87.322 us; speedup 1.0000x reference)
//
#include <hip/hip_runtime.h>
#include <cmath>

// PCEN: out = (x / (FLOOR + ema(x,w))^a + d)^(1/r) - d^(1/r), plus x_length passthrough.
// One 256-thread block per (b,c) row of T=8000. Row held in REGISTERS
// (32 elems/thread = 8 float4); EMA recurrence via shuffle-based affine scan
// (wave-level, 1 barrier total); pointwise math with raw v_exp_f32/v_log_f32.

constexpr int T_LEN = 8000;
constexpr int BLK   = 256;
constexpr int SEG   = 32;          // elements per thread segment
constexpr int NSEG  = T_LEN / SEG; // 250 active threads

__device__ __forceinline__ float fexp2(float x) { return __builtin_amdgcn_exp2f(x); }
__device__ __forceinline__ float flog2(float x) { return __builtin_amdgcn_logf(x); }

__global__ __launch_bounds__(BLK, 6) void pcen_kernel(
    const float* __restrict__ x, const float* __restrict__ alpha,
    const float* __restrict__ delta, const float* __restrict__ root,
    const float* __restrict__ ema_w, const int* __restrict__ xlen,
    float* __restrict__ out, int C, int rows, int nlen)
{
    __shared__ float wAs[4], wBs[4];

    const int tid  = threadIdx.x;
    const int lane = tid & 63;
    const int wid  = tid >> 6;
    const int row  = blockIdx.x;
    const int c    = row % C;

    const float w     = fminf(fmaxf(ema_w[c], 0.0f), 1.0f);
    const float omw   = 1.0f - w;
    const float na    = -fminf(alpha[c], 1.0f);
    const float inv_r = 1.0f / fmaxf(root[c], 1.0f);
    const float d     = delta[c];
    const float droot = fexp2(inv_r * flog2(d));

    const bool act = (tid < NSEG);

    // ---- load 32-element segment into registers (8 x float4) ----
    float4 v[8];
    const float4* xp = reinterpret_cast<const float4*>(x + (size_t)row * T_LEN + tid * SEG);
    if (act) {
        #pragma unroll
        for (int k = 0; k < 8; ++k) v[k] = xp[k];
    } else {
        #pragma unroll
        for (int k = 0; k < 8; ++k) v[k] = make_float4(0.f, 0.f, 0.f, 0.f);
    }

    // ---- pass 1: per-segment affine transform acc_out = A*acc_in + B ----
    float Bv = 0.0f;
    #pragma unroll
    for (int k = 0; k < 8; ++k) {
        Bv = fmaf(w, v[k].x, omw * Bv);
        Bv = fmaf(w, v[k].y, omw * Bv);
        Bv = fmaf(w, v[k].z, omw * Bv);
        Bv = fmaf(w, v[k].w, omw * Bv);
    }
    float t2 = omw * omw, t4 = t2 * t2, t8 = t4 * t4, t16 = t8 * t8;
    float aa = act ? (t16 * t16) : 1.0f;   // (1-w)^32, identity for idle threads
    float bb = act ? Bv : 0.0f;
    if (tid == 0) {                        // fold acc_in = x0 into thread 0's transform
        bb = fmaf(aa, v[0].x, bb);
        aa = 0.0f;
    }

    // ---- wave-level inclusive scan of affine composition (no barriers) ----
    #pragma unroll
    for (int off = 1; off < 64; off <<= 1) {
        float pa = __shfl_up(aa, off, 64);
        float pb = __shfl_up(bb, off, 64);
        if (lane >= off) { bb = fmaf(aa, pb, bb); aa *= pa; }
    }
    if (lane == 63) { wAs[wid] = aa; wBs[wid] = bb; }
    // lane-exclusive within wave
    float ea = __shfl_up(aa, 1, 64);
    float eb = __shfl_up(bb, 1, 64);
    if (lane == 0) { ea = 1.0f; eb = 0.0f; }
    __syncthreads();
    // compose aggregates of preceding waves (wave-uniform, unrolled)
    float pa = 1.0f, pb = 0.0f;
    if (wid > 0) { pb = wBs[0];                   pa = wAs[0];  }
    if (wid > 1) { pb = fmaf(wAs[1], pb, wBs[1]); pa *= wAs[1]; }
    if (wid > 2) { pb = fmaf(wAs[2], pb, wBs[2]); pa *= wAs[2]; }
    // incoming accumulator: thread 0's A=0 fold makes the x0 term propagate via B
    float ib  = fmaf(ea, pb, eb);
    float acc = (tid == 0) ? v[0].x : ib;

    // ---- pass 2: exact EMA replay + pointwise PCEN, store from registers ----
    if (act) {
        float4* op = reinterpret_cast<float4*>(out + (size_t)row * T_LEN + tid * SEG);
        #pragma unroll
        for (int k = 0; k < 8; ++k) {
            float4 u = v[k], o;
            acc = fmaf(w, u.x, omw * acc);
            o.x = fexp2(inv_r * flog2(fmaf(u.x, fexp2(na * flog2(acc + 1e-12f)), d))) - droot;
            acc = fmaf(w, u.y, omw * acc);
            o.y = fexp2(inv_r * flog2(fmaf(u.y, fexp2(na * flog2(acc + 1e-12f)), d))) - droot;
            acc = fmaf(w, u.z, omw * acc);
            o.z = fexp2(inv_r * flog2(fmaf(u.z, fexp2(na * flog2(acc + 1e-12f)), d))) - droot;
            acc = fmaf(w, u.w, omw * acc);
            o.w = fexp2(inv_r * flog2(fmaf(u.w, fexp2(na * flog2(acc + 1e-12f)), d))) - droot;
            op[k] = o;
        }
    }

    // output 1: x_length as float (harness reads whole d_out as f32)
    if (row == 0) {
        for (int i = tid; i < nlen; i += BLK)
            out[(size_t)rows * T_LEN + i] = (float)xlen[i];
    }
}

extern "C" void kernel_launch(void* const* d_in, const int* in_sizes, int n_in,
                              void* d_out, int out_size, void* d_ws, size_t ws_size,
                              hipStream_t stream) {
    const float* x     = (const float*)d_in[0];
    const float* alpha = (const float*)d_in[1];
    const float* delta = (const float*)d_in[2];
    const float* root  = (const float*)d_in[3];
    const float* emaw  = (const float*)d_in[4];
    const int*   xlen  = (const int*)d_in[5];
    float*       out   = (float*)d_out;

    const int C    = in_sizes[1];
    const int rows = in_sizes[0] / T_LEN;  // B*C
    const int nlen = in_sizes[5];

    hipLaunchKernelGGL(pcen_kernel, dim3(rows), dim3(BLK), 0, stream,
                       x, alpha, delta, root, emaw, xlen, out, C, rows, nlen);
}

// Round 4
// 71.039 us; speedup vs baseline: 1.2292x; 1.2292x over previous
//
#include <hip/hip_runtime.h>
#include <cmath>

// PCEN: out = (x / (FLOOR + ema(x,w))^a + d)^(1/r) - d^(1/r), plus x_length passthrough.
// One 256-thread block per (b,c) row of T=8000.
//   - global<->LDS staging fully coalesced (float4), swizzled placement
//   - per-thread 32-elem segment pulled LDS->registers once
//   - EMA recurrence: affine (A,B) per segment + shuffle-based wave scan (1 barrier)
//   - pointwise math with raw v_exp_f32 / v_log_f32
//   - results overwrite own LDS slots, then coalesced float4 store

constexpr int T_LEN = 8000;
constexpr int T4    = T_LEN / 4;   // 2000 float4 slots
constexpr int BLK   = 256;
constexpr int SEG   = 32;          // elements per thread segment
constexpr int NSEG  = T_LEN / SEG; // 250 active threads

__device__ __forceinline__ float fexp2(float x) { return __builtin_amdgcn_exp2f(x); }
__device__ __forceinline__ float flog2(float x) { return __builtin_amdgcn_logf(x); }

// rotate float4 slots within each 8-slot (128B) window by window index:
// staging stays contiguous; per-thread segment reads spread over all 8 bank groups
__device__ __forceinline__ int swz4(int j) {
    return (j & ~7) | ((j + (j >> 3)) & 7);
}

__global__ __launch_bounds__(BLK, 4) void pcen_kernel(
    const float* __restrict__ x, const float* __restrict__ alpha,
    const float* __restrict__ delta, const float* __restrict__ root,
    const float* __restrict__ ema_w, const int* __restrict__ xlen,
    float* __restrict__ out, int C, int rows, int nlen)
{
    __shared__ float4 lds4[T4];
    __shared__ float wAs[4], wBs[4];

    const int tid  = threadIdx.x;
    const int lane = tid & 63;
    const int wid  = tid >> 6;
    const int row  = blockIdx.x;
    const int c    = row % C;

    const float w     = fminf(fmaxf(ema_w[c], 0.0f), 1.0f);
    const float omw   = 1.0f - w;
    const float na    = -fminf(alpha[c], 1.0f);
    const float inv_r = 1.0f / fmaxf(root[c], 1.0f);
    const float d     = delta[c];
    const float droot = fexp2(inv_r * flog2(d));

    const float4* x4 = reinterpret_cast<const float4*>(x + (size_t)row * T_LEN);
    float4*       o4 = reinterpret_cast<float4*>(out + (size_t)row * T_LEN);

    // ---- stage in: coalesced global -> swizzled LDS ----
    for (int j = tid; j < T4; j += BLK) lds4[swz4(j)] = x4[j];
    __syncthreads();

    const bool act  = (tid < NSEG);
    const int  base = tid * 8;

    // ---- segment LDS -> registers ----
    float4 v[8];
    #pragma unroll
    for (int k = 0; k < 8; ++k)
        v[k] = act ? lds4[base + ((k + tid) & 7)] : make_float4(0.f, 0.f, 0.f, 0.f);

    // ---- pass 1: segment affine transform acc_out = A*acc_in + B ----
    // B = w * (((S0*p^8 + S1)*p^8 + S2)*p^8 + S3), S_g = Horner over 8 elems (4-way ILP)
    const float p  = omw;
    float S[4];
    #pragma unroll
    for (int g = 0; g < 4; ++g) {
        float4 u0 = v[2 * g], u1 = v[2 * g + 1];
        float s = u0.x;
        s = fmaf(s, p, u0.y); s = fmaf(s, p, u0.z); s = fmaf(s, p, u0.w);
        s = fmaf(s, p, u1.x); s = fmaf(s, p, u1.y); s = fmaf(s, p, u1.z);
        s = fmaf(s, p, u1.w);
        S[g] = s;
    }
    float p2 = p * p, p4 = p2 * p2, p8 = p4 * p4;
    float H = fmaf(fmaf(fmaf(S[0], p8, S[1]), p8, S[2]), p8, S[3]);
    float aa = act ? (p8 * p8 * p8 * p8) : 1.0f;  // (1-w)^32
    float bb = act ? (w * H) : 0.0f;
    if (tid == 0) {                 // fold acc_in = x0 into thread 0's transform
        bb = fmaf(aa, v[0].x, bb);
        aa = 0.0f;
    }

    // ---- wave-level inclusive scan of affine composition ----
    #pragma unroll
    for (int off = 1; off < 64; off <<= 1) {
        float pa = __shfl_up(aa, off, 64);
        float pb = __shfl_up(bb, off, 64);
        if (lane >= off) { bb = fmaf(aa, pb, bb); aa *= pa; }
    }
    if (lane == 63) { wAs[wid] = aa; wBs[wid] = bb; }
    float ea = __shfl_up(aa, 1, 64);
    float eb = __shfl_up(bb, 1, 64);
    if (lane == 0) { ea = 1.0f; eb = 0.0f; }
    __syncthreads();
    float pa = 1.0f, pb = 0.0f;
    if (wid > 0) { pb = wBs[0];                   pa = wAs[0];  }
    if (wid > 1) { pb = fmaf(wAs[1], pb, wBs[1]); pa *= wAs[1]; }
    if (wid > 2) { pb = fmaf(wAs[2], pb, wBs[2]); pa *= wAs[2]; }
    float ib  = fmaf(ea, pb, eb);       // incoming accumulator
    float acc = (tid == 0) ? v[0].x : ib;

    // ---- pass 2: exact EMA replay + pointwise PCEN, overwrite OWN LDS slots ----
    if (act) {
        #pragma unroll
        for (int k = 0; k < 8; ++k) {
            float4 u = v[k], o;
            acc = fmaf(w, u.x, omw * acc);
            o.x = fexp2(inv_r * flog2(fmaf(u.x, fexp2(na * flog2(acc + 1e-12f)), d))) - droot;
            acc = fmaf(w, u.y, omw * acc);
            o.y = fexp2(inv_r * flog2(fmaf(u.y, fexp2(na * flog2(acc + 1e-12f)), d))) - droot;
            acc = fmaf(w, u.z, omw * acc);
            o.z = fexp2(inv_r * flog2(fmaf(u.z, fexp2(na * flog2(acc + 1e-12f)), d))) - droot;
            acc = fmaf(w, u.w, omw * acc);
            o.w = fexp2(inv_r * flog2(fmaf(u.w, fexp2(na * flog2(acc + 1e-12f)), d))) - droot;
            lds4[base + ((k + tid) & 7)] = o;
        }
    }
    __syncthreads();

    // ---- stage out: swizzled LDS -> coalesced global ----
    for (int j = tid; j < T4; j += BLK) o4[j] = lds4[swz4(j)];

    // output 1: x_length as float (harness reads whole d_out as f32)
    if (row == 0) {
        for (int i = tid; i < nlen; i += BLK)
            out[(size_t)rows * T_LEN + i] = (float)xlen[i];
    }
}

extern "C" void kernel_launch(void* const* d_in, const int* in_sizes, int n_in,
                              void* d_out, int out_size, void* d_ws, size_t ws_size,
                              hipStream_t stream) {
    const float* x     = (const float*)d_in[0];
    const float* alpha = (const float*)d_in[1];
    const float* delta = (const float*)d_in[2];
    const float* root  = (const float*)d_in[3];
    const float* emaw  = (const float*)d_in[4];
    const int*   xlen  = (const int*)d_in[5];
    float*       out   = (float*)d_out;

    const int C    = in_sizes[1];
    const int rows = in_sizes[0] / T_LEN;  // B*C
    const int nlen = in_sizes[5];

    hipLaunchKernelGGL(pcen_kernel, dim3(rows), dim3(BLK), 0, stream,
                       x, alpha, delta, root, emaw, xlen, out, C, rows, nlen);
}

// Round 5
// 65.841 us; speedup vs baseline: 1.3263x; 1.0789x over previous
//
#include <hip/hip_runtime.h>
#include <cmath>

// PCEN: out = (x / (FLOOR + ema(x,w))^a + d)^(1/r) - d^(1/r), plus x_length passthrough.
// One 256-thread block per (b,c) row of T=8000, processed as 8 tiles of 1024 elems.
// Each thread owns ONE float4 per tile -> per-thread-contiguous == coalesced, so no
// LDS row staging at all. EMA recurrence: uniform-coefficient Kogge-Stone scan with
// constant multipliers (6 shfl + 6 fma), 4-float LDS wave-aggregate combine
// (parity double-buffered, 1 barrier/tile), inter-tile carry computed uniformly.
// Pointwise math: raw v_log_f32/v_exp_f32; root==2 fast path via v_sqrt_f32.

constexpr int T_LEN = 8000;
constexpr int T4    = T_LEN / 4;               // 2000 float4 per row
constexpr int BLK   = 256;
constexpr int NTILE = (T4 + BLK - 1) / BLK;    // 8 tiles

__device__ __forceinline__ float fexp2(float x) { return __builtin_amdgcn_exp2f(x); }
__device__ __forceinline__ float flog2(float x) { return __builtin_amdgcn_logf(x); }
__device__ __forceinline__ float fsqrt(float x) { return __builtin_amdgcn_sqrtf(x); }

__global__ __launch_bounds__(BLK, 8) void pcen_kernel(
    const float* __restrict__ x, const float* __restrict__ alpha,
    const float* __restrict__ delta, const float* __restrict__ root,
    const float* __restrict__ ema_w, const int* __restrict__ xlen,
    float* __restrict__ out, int C, int rows, int nlen)
{
    __shared__ float wB[2][4];   // per-tile wave aggregates (parity double-buffered)

    const int tid  = threadIdx.x;
    const int lane = tid & 63;
    const int wid  = tid >> 6;
    const int row  = blockIdx.x;
    const int c    = row % C;

    const float w     = fminf(fmaxf(ema_w[c], 0.0f), 1.0f);
    const float p     = 1.0f - w;              // EMA decay
    const float na    = -fminf(alpha[c], 1.0f);
    const float r     = fmaxf(root[c], 1.0f);
    const float inv_r = 1.0f / r;
    const float d     = delta[c];
    const bool  use_sqrt = (r == 2.0f);
    const float droot = use_sqrt ? fsqrt(d) : fexp2(inv_r * flog2(d));

    // scan constants by repeated squaring (no log hazards)
    const float p4 = p * p * p * p;            // per-thread segment decay
    const float c1 = p4, c2 = c1 * c1, c3 = c2 * c2,
                c4 = c3 * c3, c5 = c4 * c4, c6 = c5 * c5;  // p^4..p^128
    const float q  = c6 * c6;                  // p^256 (per-wave decay)
    const float q2 = q * q, q3 = q2 * q, q4 = q2 * q2;     // p^512, p^768, p^1024
    // p^(4*lane): exp2(4*lane*log2 p); lane==0 select avoids 0*(-inf)=NaN when p==0
    const float lp  = flog2(p);
    const float p4l = (lane == 0) ? 1.0f : fexp2(4.0f * (float)lane * lp);
    const float qw  = (wid == 0) ? 1.0f : (wid == 1) ? q : (wid == 2) ? q2 : q3;

    const float4* x4 = reinterpret_cast<const float4*>(x + (size_t)row * T_LEN);
    float4*       o4 = reinterpret_cast<float4*>(out + (size_t)row * T_LEN);

    float carry = x[(size_t)row * T_LEN];      // jax scan init: acc = x[...,0]

    float4 v = (tid < T4) ? x4[tid] : make_float4(0.f, 0.f, 0.f, 0.f);

    for (int t = 0; t < NTILE; ++t) {
        const int  j      = t * BLK + tid;
        const bool active = (j < T4);
        const int  par    = t & 1;

        // ---- per-thread transform: B = w * Horner over own 4 elems ----
        float s = v.x;
        s = fmaf(s, p, v.y); s = fmaf(s, p, v.z); s = fmaf(s, p, v.w);
        float b = active ? (w * s) : 0.0f;

        // ---- Kogge-Stone inclusive scan, constant multipliers ----
        float pb;
        pb = __shfl_up(b,  1, 64); if (lane >=  1) b = fmaf(c1, pb, b);
        pb = __shfl_up(b,  2, 64); if (lane >=  2) b = fmaf(c2, pb, b);
        pb = __shfl_up(b,  4, 64); if (lane >=  4) b = fmaf(c3, pb, b);
        pb = __shfl_up(b,  8, 64); if (lane >=  8) b = fmaf(c4, pb, b);
        pb = __shfl_up(b, 16, 64); if (lane >= 16) b = fmaf(c5, pb, b);
        pb = __shfl_up(b, 32, 64); if (lane >= 32) b = fmaf(c6, pb, b);

        if (lane == 63) wB[par][wid] = b;
        float eb = __shfl_up(b, 1, 64);
        if (lane == 0) eb = 0.0f;
        __syncthreads();

        // ---- prefetch next tile (issued early; consumed next iteration) ----
        float4 vn = make_float4(0.f, 0.f, 0.f, 0.f);
        const int jn = j + BLK;
        if (jn < T4) vn = x4[jn];

        // ---- compose wave prefix + inter-tile carry (uniform) ----
        const float W0 = wB[par][0], W1 = wB[par][1], W2 = wB[par][2], W3 = wB[par][3];
        float Pb = 0.0f;
        if (wid == 1) Pb = W0;
        else if (wid == 2) Pb = fmaf(q, W0, W1);
        else if (wid == 3) Pb = fmaf(q, fmaf(q, W0, W1), W2);
        const float base = fmaf(qw, carry, Pb);
        float acc = fmaf(p4l, base, eb);       // acc entering this thread's 4 elems

        const float Tb = fmaf(q, fmaf(q, fmaf(q, W0, W1), W2), W3);
        carry = fmaf(q4, carry, Tb);           // p^1024 * carry + tile total

        // ---- pass 2: exact EMA replay + pointwise PCEN, direct coalesced store ----
        if (active) {
            float4 u = v, o;
            if (use_sqrt) {
                acc = fmaf(w, u.x, p * acc);
                o.x = fsqrt(fmaf(u.x, fexp2(na * flog2(acc + 1e-12f)), d)) - droot;
                acc = fmaf(w, u.y, p * acc);
                o.y = fsqrt(fmaf(u.y, fexp2(na * flog2(acc + 1e-12f)), d)) - droot;
                acc = fmaf(w, u.z, p * acc);
                o.z = fsqrt(fmaf(u.z, fexp2(na * flog2(acc + 1e-12f)), d)) - droot;
                acc = fmaf(w, u.w, p * acc);
                o.w = fsqrt(fmaf(u.w, fexp2(na * flog2(acc + 1e-12f)), d)) - droot;
            } else {
                acc = fmaf(w, u.x, p * acc);
                o.x = fexp2(inv_r * flog2(fmaf(u.x, fexp2(na * flog2(acc + 1e-12f)), d))) - droot;
                acc = fmaf(w, u.y, p * acc);
                o.y = fexp2(inv_r * flog2(fmaf(u.y, fexp2(na * flog2(acc + 1e-12f)), d))) - droot;
                acc = fmaf(w, u.z, p * acc);
                o.z = fexp2(inv_r * flog2(fmaf(u.z, fexp2(na * flog2(acc + 1e-12f)), d))) - droot;
                acc = fmaf(w, u.w, p * acc);
                o.w = fexp2(inv_r * flog2(fmaf(u.w, fexp2(na * flog2(acc + 1e-12f)), d))) - droot;
            }
            o4[j] = o;
        }
        v = vn;
    }

    // output 1: x_length as float (harness reads whole d_out as f32)
    if (row == 0) {
        for (int i = tid; i < nlen; i += BLK)
            out[(size_t)rows * T_LEN + i] = (float)xlen[i];
    }
}

extern "C" void kernel_launch(void* const* d_in, const int* in_sizes, int n_in,
                              void* d_out, int out_size, void* d_ws, size_t ws_size,
                              hipStream_t stream) {
    const float* x     = (const float*)d_in[0];
    const float* alpha = (const float*)d_in[1];
    const float* delta = (const float*)d_in[2];
    const float* root  = (const float*)d_in[3];
    const float* emaw  = (const float*)d_in[4];
    const int*   xlen  = (const int*)d_in[5];
    float*       out   = (float*)d_out;

    const int C    = in_sizes[1];
    const int rows = in_sizes[0] / T_LEN;  // B*C
    const int nlen = in_sizes[5];

    hipLaunchKernelGGL(pcen_kernel, dim3(rows), dim3(BLK), 0, stream,
                       x, alpha, delta, root, emaw, xlen, out, C, rows, nlen);
}